// Round 8
// baseline (607.802 us; speedup 1.0000x reference)
//
#include <hip/hip_runtime.h>
#include <cstdint>
#include <cstddef>

typedef __bf16 bf16x8 __attribute__((ext_vector_type(8)));
typedef float  f32x4  __attribute__((ext_vector_type(4)));

#define MFMA16(a,b,c) __builtin_amdgcn_mfma_f32_16x16x32_bf16((a),(b),(c),0,0,0)

// ---------- helpers ----------
__device__ __forceinline__ uint f2bf1(float f){
  uint u = __builtin_bit_cast(uint, f);
  u += 0x7FFFu + ((u >> 16) & 1u);   // RNE to bf16
  return u >> 16;
}
__device__ __forceinline__ uint pack2(float a, float b){  // RNE (cold paths)
  return f2bf1(a) | (f2bf1(b) << 16);
}
// fast pack: round-half-away via biased add + v_perm_b32 (3 VALU ops)
__device__ __forceinline__ uint pack2f(float a, float b){
  uint ua = __builtin_bit_cast(uint, a) + 0x8000u;
  uint ub = __builtin_bit_cast(uint, b) + 0x8000u;
  return __builtin_amdgcn_perm(ub, ua, 0x07060302u); // {ua.b2,ua.b3,ub.b2,ub.b3}
}
__device__ __forceinline__ float bflo(uint d){ return __builtin_bit_cast(float, d << 16); }
__device__ __forceinline__ float bfhi(uint d){ return __builtin_bit_cast(float, d & 0xFFFF0000u); }

// =====================================================================
// Kernel 1: blocks [0,3072) transpose triplane fp32->bf16
// (B,3,C,H,W)->(B,3,H,W,C); blocks [3072,3106) pack weights into MFMA
// A-frag order.  Unchanged.
// wpk sections (uint4): 0 dw1T,2048 cw1T,4096 w2dT,6144 w2cT,
//                       8192 w3dT(256),8448 w3cT(256)
// =====================================================================
__global__ __launch_bounds__(256, 4) void prep_k(
    const float* __restrict__ tri, ushort* __restrict__ tp,
    const float* __restrict__ dw1, const float* __restrict__ cw1,
    const float* __restrict__ dw2, const float* __restrict__ cw2,
    const float* __restrict__ dw3, const float* __restrict__ cw3,
    uint4* __restrict__ wpk)
{
  __shared__ uint stu[40 * 130];      // 20.8 KB
  const int tid = threadIdx.x;
  if (blockIdx.x < 3072){
    const int y = blockIdx.x & 255;
    const int q = blockIdx.x >> 8;             // b*3+pl, 0..11
    const float* src = tri + (size_t)q * 40 * 65536 + y * 256;
#pragma unroll
    for (int it = 0; it < 10; it++){
      int lin = it * 256 + tid;                // 0..2559
      int c = lin >> 6, xq = lin & 63;
      const float4 v = *(const float4*)(src + (size_t)c * 65536 + xq * 4);
      uint2 w; w.x = pack2(v.x, v.y); w.y = pack2(v.z, v.w);
      *(uint2*)&stu[c * 130 + 2 * xq] = w;     // x = 4*xq+i  ->  us[c*260 + x]
    }
    __syncthreads();
    uint4* dst = (uint4*)(tp + ((size_t)q * 65536 + (size_t)y * 256) * 40);
#pragma unroll
    for (int it = 0; it < 5; it++){
      int m = it * 256 + tid;                  // uint4 index 0..1279
      uint4 o;
#pragma unroll
      for (int jj = 0; jj < 4; jj++){
        int d  = 4 * m + jj;                   // output dword 0..5119
        int x  = (d * 3277) >> 16;             // d/20, exact for d<5120
        int cp = d - x * 20;                   // c = 2*cp
        uint A = stu[(2 * cp    ) * 130 + (x >> 1)];
        uint B = stu[(2 * cp + 1) * 130 + (x >> 1)];
        ((uint*)&o)[jj] = (x & 1) ? ((A >> 16)      | (B & 0xFFFF0000u))
                                  : ((A & 0xFFFFu)  | (B << 16));
      }
      dst[m] = o;
    }
  } else {
    int idx = (blockIdx.x - 3072) * 256 + tid;
    if (idx >= 8704) return;
    int mode, rel;
    if      (idx < 2048){ mode = 0; rel = idx; }
    else if (idx < 4096){ mode = 1; rel = idx - 2048; }
    else if (idx < 6144){ mode = 2; rel = idx - 4096; }
    else if (idx < 8192){ mode = 3; rel = idx - 6144; }
    else if (idx < 8448){ mode = 4; rel = idx - 8192; }
    else                { mode = 5; rel = idx - 8448; }
    int frag = rel >> 6, lane = rel & 63;
    int Mt = frag >> 2, s = frag & 3;
    int m  = Mt * 16 + (lane & 15);
    int kb = s * 32 + (lane >> 4) * 8;
    uint d[4];
#pragma unroll
    for (int jj = 0; jj < 4; jj++){
      float v0 = 0.f, v1 = 0.f;
#pragma unroll
      for (int h = 0; h < 2; h++){
        int k = kb + jj * 2 + h;
        float v = 0.f;
        switch (mode){
          case 0: v = (k < 120) ? dw1[k * 128 + m] : 0.f; break;
          case 1: v = (k < 123) ? cw1[k * 128 + m] : 0.f; break;
          case 2: v = dw2[k * 128 + m]; break;
          case 3: v = cw2[k * 128 + m]; break;
          case 4: v = (m == 0) ? dw3[k] : 0.f; break;
          default: v = (m >= 1 && m <= 3) ? cw3[k * 3 + (m - 1)] : 0.f; break;
        }
        if (h == 0) v0 = v; else v1 = v;
      }
      d[jj] = pack2(v0, v1);
    }
    uint4 o; o.x = d[0]; o.y = d[1]; o.z = d[2]; o.w = d[3];
    wpk[idx] = o;
  }
}

// =====================================================================
// Kernel 2 (round 8): R7's staged-weight pipeline at QUARTER
// granularity.  R7 (half granularity, 64KB LDS, 2 blocks/CU) hit its
// predicted 382us and confirmed: binder = waves/CU (latency hiding),
// VALU busiest at 38.9%.  Now: 2 x 8KB weight dbuf (quarter-layer =
// 2 Mt-tiles = 8 frags), LDS = 32KB h + 16KB = 48KB -> THREE blocks/CU
// = 12 waves/CU.  19-phase ladder, 16 MFMA/phase; per-phase compute
// (~300cy) covers the L2 stage latency, 3rd block fills the residue.
// Stage bytes unchanged (weights staged once; only chunk size halves).
// =====================================================================
__device__ __forceinline__ uint4 blend4(uint4 a, uint4 b, uint4 c, uint4 d,
                                        float w00, float w10, float w01, float w11){
  uint4 ov;
  ov.x = pack2f(w00*bflo(a.x)+w10*bflo(b.x)+w01*bflo(c.x)+w11*bflo(d.x),
                w00*bfhi(a.x)+w10*bfhi(b.x)+w01*bfhi(c.x)+w11*bfhi(d.x));
  ov.y = pack2f(w00*bflo(a.y)+w10*bflo(b.y)+w01*bflo(c.y)+w11*bflo(d.y),
                w00*bfhi(a.y)+w10*bfhi(b.y)+w01*bfhi(c.y)+w11*bfhi(d.y));
  ov.z = pack2f(w00*bflo(a.z)+w10*bflo(b.z)+w01*bflo(c.z)+w11*bflo(d.z),
                w00*bfhi(a.z)+w10*bfhi(b.z)+w01*bfhi(c.z)+w11*bfhi(d.z));
  ov.w = pack2f(w00*bflo(a.w)+w10*bflo(b.w)+w01*bflo(c.w)+w11*bflo(d.w),
                w00*bfhi(a.w)+w10*bfhi(b.w)+w01*bfhi(c.w)+w11*bfhi(d.w));
  return ov;
}

// h layout: row (t*16+lrow) has 64 dwords (128 units); rotation swizzle.
__device__ __forceinline__ bf16x8 read_h(const uint* S, int s, int t, int lrow, int lq){
  int dwb = (s * 16 + lq * 4 + (lrow << 2)) & 63;
  return __builtin_bit_cast(bf16x8, *(const uint4*)&S[(t * 16 + lrow) * 64 + dwb]);
}

__device__ __forceinline__ void put_h(uint* S, f32x4 v, int Mt, int t, int lrow, int lq){
  uint2 w;
  w.x = pack2f(fmaxf(v[0], 0.f), fmaxf(v[1], 0.f));
  w.y = pack2f(fmaxf(v[2], 0.f), fmaxf(v[3], 0.f));
  int dw = (Mt * 8 + lq * 2 + (lrow << 2)) & 63;
  *(uint2*)&S[(t * 16 + lrow) * 64 + dw] = w;
}

// block-cooperative async stage of nchunk*64 uint4 into LDS (4 waves)
__device__ __forceinline__ void stage16(const uint4* __restrict__ g, uint4* l,
                                        int wave, int lane, int nchunk){
  for (int c = wave; c < nchunk; c += 4){
    __builtin_amdgcn_global_load_lds(
      (const __attribute__((address_space(1))) void*)(g + c * 64 + lane),
      (__attribute__((address_space(3))) void*)(l + c * 64 + lane), 16, 0, 0);
  }
}

// one quarter (2 Mt-tiles) of an input layer: B-frags from registers.
// W = 8-frag quarter buffer (local frag index mt*4+s); global Mt = q*2+mt.
__device__ __forceinline__ void layer1_q(uint* S, const uint4* W,
                                         const float* __restrict__ bias,
                                         const uint4 (&bf)[4][2], int q,
                                         int lrow, int lq, int lane){
  f32x4 acc[2][2];
#pragma unroll
  for (int mt = 0; mt < 2; mt++){
    f32x4 bi = *(const f32x4*)(bias + (q * 2 + mt) * 16 + lq * 4);
    acc[mt][0] = bi; acc[mt][1] = bi;
  }
#pragma unroll
  for (int s = 0; s < 4; s++)
#pragma unroll
    for (int mt = 0; mt < 2; mt++){
      bf16x8 aw = __builtin_bit_cast(bf16x8, W[(mt * 4 + s) * 64 + lane]);
      acc[mt][0] = MFMA16(aw, __builtin_bit_cast(bf16x8, bf[s][0]), acc[mt][0]);
      acc[mt][1] = MFMA16(aw, __builtin_bit_cast(bf16x8, bf[s][1]), acc[mt][1]);
    }
#pragma unroll
  for (int mt = 0; mt < 2; mt++){
    put_h(S, acc[mt][0], q * 2 + mt, 0, lrow, lq);
    put_h(S, acc[mt][1], q * 2 + mt, 1, lrow, lq);
  }
}

__device__ __forceinline__ void load_hb(const uint* S, bf16x8 (&hb)[4][2],
                                        int lrow, int lq){
#pragma unroll
  for (int s = 0; s < 4; s++){
    hb[s][0] = read_h(S, s, 0, lrow, lq);
    hb[s][1] = read_h(S, s, 1, lrow, lq);
  }
}

// one quarter of a dense layer: B-frags preloaded (hb), writes in place
__device__ __forceinline__ void dense_q(uint* S, const uint4* W,
                                        const float* __restrict__ bias,
                                        const bf16x8 (&hb)[4][2], int q,
                                        int lrow, int lq, int lane){
  f32x4 acc[2][2];
#pragma unroll
  for (int mt = 0; mt < 2; mt++){
    f32x4 bi = *(const f32x4*)(bias + (q * 2 + mt) * 16 + lq * 4);
    acc[mt][0] = bi; acc[mt][1] = bi;
  }
#pragma unroll
  for (int s = 0; s < 4; s++)
#pragma unroll
    for (int mt = 0; mt < 2; mt++){
      bf16x8 aw = __builtin_bit_cast(bf16x8, W[(mt * 4 + s) * 64 + lane]);
      acc[mt][0] = MFMA16(aw, hb[s][0], acc[mt][0]);
      acc[mt][1] = MFMA16(aw, hb[s][1], acc[mt][1]);
    }
#pragma unroll
  for (int mt = 0; mt < 2; mt++){
    put_h(S, acc[mt][0], q * 2 + mt, 0, lrow, lq);
    put_h(S, acc[mt][1], q * 2 + mt, 1, lrow, lq);
  }
}

__device__ __forceinline__ void out_l(const uint* S, const uint4* W,
                                      f32x4 (&acc3)[2], int lrow, int lq, int lane){
#pragma unroll
  for (int s = 0; s < 4; s++){
    bf16x8 aw = __builtin_bit_cast(bf16x8, W[s * 64 + lane]);
    acc3[0] = MFMA16(aw, read_h(S, s, 0, lrow, lq), acc3[0]);
    acc3[1] = MFMA16(aw, read_h(S, s, 1, lrow, lq), acc3[1]);
  }
}

__global__ __launch_bounds__(256, 2) void fused_k(
    const ushort* __restrict__ tp, const float* __restrict__ coords,
    const float* __restrict__ vdirs, const uint4* __restrict__ wpk,
    const float* __restrict__ db1, const float* __restrict__ db2,
    const float* __restrict__ db3, const float* __restrict__ cb1,
    const float* __restrict__ cb2, const float* __restrict__ cb3,
    float* __restrict__ out)
{
  __shared__ uint  Sh[4][2048];                 // 32 KB: 8 KB wave-private h
  __shared__ uint4 WB[2][512];                  // 2 x 8 KB weight dbuf
  const int wave = threadIdx.x >> 6;            // 0..3
  uint* S = Sh[wave];
  const int lane = threadIdx.x & 63, lrow = lane & 15, lq = lane >> 4;
  const int blk   = blockIdx.x;                 // 0..8191
  const int pbase = (blk & 3) * 262144 + (blk >> 2) * 128 + wave * 32;

  // P0: stage dw1.q0 -> B0, under the gather
  stage16(wpk + 0, WB[0], wave, lane, 8);

  // ---- fused gather: build B-frags directly in registers ----
  uint4 bf[4][2];
#pragma unroll
  for (int t = 0; t < 2; t++){
    const int p  = pbase + t * 16 + lrow;
    const int bb = p >> 18;                          // N = 2^18
    const float cx = coords[3 * p], cy = coords[3 * p + 1], cz = coords[3 * p + 2];
    float pw00[3], pw10[3], pw01[3], pw11[3];
    uint  o00[3], o10[3], o01[3], o11[3];
#pragma unroll
    for (int pl = 0; pl < 3; pl++){
      const float u = (pl == 2) ? cy : cx;
      const float v = (pl == 0) ? cy : cz;
      float ix = fmaf(u, 128.f, 127.5f);
      float iy = fmaf(v, 128.f, 127.5f);
      float fx0 = floorf(ix), fy0 = floorf(iy);
      float fx = ix - fx0, fy = iy - fy0;
      int x0 = (int)fx0, y0 = (int)fy0;
      float wx0 = (x0 >= 0  && x0 < 256) ? (1.f - fx) : 0.f;
      float wx1 = (x0 >= -1 && x0 < 255) ? fx : 0.f;
      float wy0 = (y0 >= 0  && y0 < 256) ? (1.f - fy) : 0.f;
      float wy1 = (y0 >= -1 && y0 < 255) ? fy : 0.f;
      int xc0 = min(max(x0, 0), 255), xc1 = min(max(x0 + 1, 0), 255);
      int yc0 = min(max(y0, 0), 255), yc1 = min(max(y0 + 1, 0), 255);
      pw00[pl] = wx0 * wy0; pw10[pl] = wx1 * wy0;
      pw01[pl] = wx0 * wy1; pw11[pl] = wx1 * wy1;
      o00[pl] = ((uint)yc0 * 256u + (uint)xc0) * 40u;
      o10[pl] = ((uint)yc0 * 256u + (uint)xc1) * 40u;
      o01[pl] = ((uint)yc1 * 256u + (uint)xc0) * 40u;
      o11[pl] = ((uint)yc1 * 256u + (uint)xc1) * 40u;
    }
#pragma unroll
    for (int s = 0; s < 4; s++){
      const int chunk = s * 4 + lq;        // channel chunk = [chunk*8, chunk*8+7]
      if (chunk == 15){                    // vd + pad (only lq==3, s==3)
        const float v0 = vdirs[3 * p], v1 = vdirs[3 * p + 1], v2 = vdirs[3 * p + 2];
        uint4 tt; tt.x = pack2f(v0, v1); tt.y = pack2f(v2, 0.f); tt.z = 0u; tt.w = 0u;
        bf[s][t] = tt;
      } else {
        const int pl = (chunk < 5) ? 0 : (chunk < 10) ? 1 : 2;
        const int c0 = chunk * 8 - pl * 40;   // local channel offset in plane row
        const ushort* base = tp + (size_t)(bb * 3 + pl) * 2621440 + c0;
        uint4 a = *(const uint4*)(base + o00[pl]);
        uint4 b = *(const uint4*)(base + o10[pl]);
        uint4 c = *(const uint4*)(base + o01[pl]);
        uint4 d = *(const uint4*)(base + o11[pl]);
        bf[s][t] = blend4(a, b, c, d, pw00[pl], pw10[pl], pw01[pl], pw11[pl]);
      }
    }
  }

  f32x4 acc3[2];
  {
    float i0 = (lq == 0) ? db3[0] : 0.f;
    float i1 = (lq == 0) ? cb3[0] : 0.f;
    float i2 = (lq == 0) ? cb3[1] : 0.f;
    float i3 = (lq == 0) ? cb3[2] : 0.f;
    f32x4 iv = {i0, i1, i2, i3};
    acc3[0] = iv; acc3[1] = iv;
  }

  __syncthreads();                                   // B0 = dw1.q0 ready
  // P1
  stage16(wpk + 512, WB[1], wave, lane, 8);          // dw1.q1 -> B1
  layer1_q(S, WB[0], db1, bf, 0, lrow, lq, lane);
  __syncthreads();
  // P2
  stage16(wpk + 1024, WB[0], wave, lane, 8);         // dw1.q2 -> B0
  layer1_q(S, WB[1], db1, bf, 1, lrow, lq, lane);
  __syncthreads();
  // P3
  stage16(wpk + 1536, WB[1], wave, lane, 8);         // dw1.q3 -> B1
  layer1_q(S, WB[0], db1, bf, 2, lrow, lq, lane);
  __syncthreads();
  // P4
  stage16(wpk + 4096, WB[0], wave, lane, 8);         // w2d.q0 -> B0
  layer1_q(S, WB[1], db1, bf, 3, lrow, lq, lane);
  __syncthreads();
  // P5
  stage16(wpk + 4608, WB[1], wave, lane, 8);         // w2d.q1 -> B1
  bf16x8 hb[4][2];
  load_hb(S, hb, lrow, lq);                          // before in-place writes
  dense_q(S, WB[0], db2, hb, 0, lrow, lq, lane);
  __syncthreads();
  // P6
  stage16(wpk + 5120, WB[0], wave, lane, 8);         // w2d.q2 -> B0
  dense_q(S, WB[1], db2, hb, 1, lrow, lq, lane);
  __syncthreads();
  // P7
  stage16(wpk + 5632, WB[1], wave, lane, 8);         // w2d.q3 -> B1
  dense_q(S, WB[0], db2, hb, 2, lrow, lq, lane);
  __syncthreads();
  // P8
  stage16(wpk + 8192, WB[0], wave, lane, 4);         // w3d -> B0 (4KB)
  dense_q(S, WB[1], db2, hb, 3, lrow, lq, lane);
  __syncthreads();
  // P9
  stage16(wpk + 2048, WB[1], wave, lane, 8);         // w1c.q0 -> B1
  out_l(S, WB[0], acc3, lrow, lq, lane);             // density
  __syncthreads();
  // P10
  stage16(wpk + 2560, WB[0], wave, lane, 8);         // w1c.q1 -> B0
  layer1_q(S, WB[1], cb1, bf, 0, lrow, lq, lane);
  __syncthreads();
  // P11
  stage16(wpk + 3072, WB[1], wave, lane, 8);         // w1c.q2 -> B1
  layer1_q(S, WB[0], cb1, bf, 1, lrow, lq, lane);
  __syncthreads();
  // P12
  stage16(wpk + 3584, WB[0], wave, lane, 8);         // w1c.q3 -> B0
  layer1_q(S, WB[1], cb1, bf, 2, lrow, lq, lane);
  __syncthreads();
  // P13
  stage16(wpk + 6144, WB[1], wave, lane, 8);         // w2c.q0 -> B1
  layer1_q(S, WB[0], cb1, bf, 3, lrow, lq, lane);
  __syncthreads();
  // P14
  stage16(wpk + 6656, WB[0], wave, lane, 8);         // w2c.q1 -> B0
  bf16x8 hb2[4][2];
  load_hb(S, hb2, lrow, lq);
  dense_q(S, WB[1], cb2, hb2, 0, lrow, lq, lane);
  __syncthreads();
  // P15
  stage16(wpk + 7168, WB[1], wave, lane, 8);         // w2c.q2 -> B1
  dense_q(S, WB[0], cb2, hb2, 1, lrow, lq, lane);
  __syncthreads();
  // P16
  stage16(wpk + 7680, WB[0], wave, lane, 8);         // w2c.q3 -> B0
  dense_q(S, WB[1], cb2, hb2, 2, lrow, lq, lane);
  __syncthreads();
  // P17
  stage16(wpk + 8448, WB[1], wave, lane, 4);         // w3c -> B1 (4KB)
  dense_q(S, WB[0], cb2, hb2, 3, lrow, lq, lane);
  __syncthreads();
  // P18
  out_l(S, WB[1], acc3, lrow, lq, lane);             // rgb

  if (lq == 0){
#pragma unroll
    for (int t = 0; t < 2; t++){
      int p = pbase + t * 16 + lrow;
      out[p] = acc3[t][0];
      float* rgb = out + 1048576 + (size_t)p * 3;
      rgb[0] = 1.f / (1.f + __expf(-acc3[t][1]));
      rgb[1] = 1.f / (1.f + __expf(-acc3[t][2]));
      rgb[2] = 1.f / (1.f + __expf(-acc3[t][3]));
    }
  }
}

// =====================================================================
extern "C" void kernel_launch(void* const* d_in, const int* in_sizes, int n_in,
                              void* d_out, int out_size, void* d_ws, size_t ws_size,
                              hipStream_t stream)
{
  (void)in_sizes; (void)n_in; (void)out_size; (void)ws_size;
  const float* tri    = (const float*)d_in[0];
  const float* coords = (const float*)d_in[1];
  const float* vdirs  = (const float*)d_in[2];
  const float* dw1 = (const float*)d_in[3];  const float* db1 = (const float*)d_in[4];
  const float* dw2 = (const float*)d_in[5];  const float* db2 = (const float*)d_in[6];
  const float* dw3 = (const float*)d_in[7];  const float* db3 = (const float*)d_in[8];
  const float* cw1 = (const float*)d_in[9];  const float* cb1 = (const float*)d_in[10];
  const float* cw2 = (const float*)d_in[11]; const float* cb2 = (const float*)d_in[12];
  const float* cw3 = (const float*)d_in[13]; const float* cb3 = (const float*)d_in[14];

  char* ws = (char*)d_ws;
  const size_t planes_bytes = 62914560;   // 4*3*256*256*40*2
  ushort* tp  = (ushort*)ws;
  uint4*  wpk = (uint4*)(ws + planes_bytes);

  prep_k<<<3106, 256, 0, stream>>>(tri, tp, dw1, cw1, dw2, cw2, dw3, cw3, wpk);
  fused_k<<<8192, 256, 0, stream>>>(tp, coords, vdirs, wpk,
                                    db1, db2, db3, cb1, cb2, cb3,
                                    (float*)d_out);
}

// Round 9
// 578.802 us; speedup vs baseline: 1.0501x; 1.0501x over previous
//
#include <hip/hip_runtime.h>
#include <cstdint>
#include <cstddef>

typedef __bf16 bf16x8 __attribute__((ext_vector_type(8)));
typedef float  f32x4  __attribute__((ext_vector_type(4)));

#define MFMA16(a,b,c) __builtin_amdgcn_mfma_f32_16x16x32_bf16((a),(b),(c),0,0,0)

// ---------- helpers ----------
__device__ __forceinline__ uint f2bf1(float f){
  uint u = __builtin_bit_cast(uint, f);
  u += 0x7FFFu + ((u >> 16) & 1u);   // RNE to bf16
  return u >> 16;
}
__device__ __forceinline__ uint pack2(float a, float b){  // RNE (cold paths)
  return f2bf1(a) | (f2bf1(b) << 16);
}
// fast pack: round-half-away via biased add + v_perm_b32 (3 VALU ops)
__device__ __forceinline__ uint pack2f(float a, float b){
  uint ua = __builtin_bit_cast(uint, a) + 0x8000u;
  uint ub = __builtin_bit_cast(uint, b) + 0x8000u;
  return __builtin_amdgcn_perm(ub, ua, 0x07060302u); // {ua.b2,ua.b3,ub.b2,ub.b3}
}
__device__ __forceinline__ float bflo(uint d){ return __builtin_bit_cast(float, d << 16); }
__device__ __forceinline__ float bfhi(uint d){ return __builtin_bit_cast(float, d & 0xFFFF0000u); }

// =====================================================================
// Kernel 1: blocks [0,3072) transpose triplane fp32->bf16
// (B,3,C,H,W)->(B,3,H,W,C); blocks [3072,3106) pack weights into MFMA
// A-frag order.  Unchanged.
// wpk sections (uint4): 0 dw1T,2048 cw1T,4096 w2dT,6144 w2cT,
//                       8192 w3dT(256),8448 w3cT(256)
// =====================================================================
__global__ __launch_bounds__(256, 4) void prep_k(
    const float* __restrict__ tri, ushort* __restrict__ tp,
    const float* __restrict__ dw1, const float* __restrict__ cw1,
    const float* __restrict__ dw2, const float* __restrict__ cw2,
    const float* __restrict__ dw3, const float* __restrict__ cw3,
    uint4* __restrict__ wpk)
{
  __shared__ uint stu[40 * 130];      // 20.8 KB
  const int tid = threadIdx.x;
  if (blockIdx.x < 3072){
    const int y = blockIdx.x & 255;
    const int q = blockIdx.x >> 8;             // b*3+pl, 0..11
    const float* src = tri + (size_t)q * 40 * 65536 + y * 256;
#pragma unroll
    for (int it = 0; it < 10; it++){
      int lin = it * 256 + tid;                // 0..2559
      int c = lin >> 6, xq = lin & 63;
      const float4 v = *(const float4*)(src + (size_t)c * 65536 + xq * 4);
      uint2 w; w.x = pack2(v.x, v.y); w.y = pack2(v.z, v.w);
      *(uint2*)&stu[c * 130 + 2 * xq] = w;     // x = 4*xq+i  ->  us[c*260 + x]
    }
    __syncthreads();
    uint4* dst = (uint4*)(tp + ((size_t)q * 65536 + (size_t)y * 256) * 40);
#pragma unroll
    for (int it = 0; it < 5; it++){
      int m = it * 256 + tid;                  // uint4 index 0..1279
      uint4 o;
#pragma unroll
      for (int jj = 0; jj < 4; jj++){
        int d  = 4 * m + jj;                   // output dword 0..5119
        int x  = (d * 3277) >> 16;             // d/20, exact for d<5120
        int cp = d - x * 20;                   // c = 2*cp
        uint A = stu[(2 * cp    ) * 130 + (x >> 1)];
        uint B = stu[(2 * cp + 1) * 130 + (x >> 1)];
        ((uint*)&o)[jj] = (x & 1) ? ((A >> 16)      | (B & 0xFFFF0000u))
                                  : ((A & 0xFFFFu)  | (B << 16));
      }
      dst[m] = o;
    }
  } else {
    int idx = (blockIdx.x - 3072) * 256 + tid;
    if (idx >= 8704) return;
    int mode, rel;
    if      (idx < 2048){ mode = 0; rel = idx; }
    else if (idx < 4096){ mode = 1; rel = idx - 2048; }
    else if (idx < 6144){ mode = 2; rel = idx - 4096; }
    else if (idx < 8192){ mode = 3; rel = idx - 6144; }
    else if (idx < 8448){ mode = 4; rel = idx - 8192; }
    else                { mode = 5; rel = idx - 8448; }
    int frag = rel >> 6, lane = rel & 63;
    int Mt = frag >> 2, s = frag & 3;
    int m  = Mt * 16 + (lane & 15);
    int kb = s * 32 + (lane >> 4) * 8;
    uint d[4];
#pragma unroll
    for (int jj = 0; jj < 4; jj++){
      float v0 = 0.f, v1 = 0.f;
#pragma unroll
      for (int h = 0; h < 2; h++){
        int k = kb + jj * 2 + h;
        float v = 0.f;
        switch (mode){
          case 0: v = (k < 120) ? dw1[k * 128 + m] : 0.f; break;
          case 1: v = (k < 123) ? cw1[k * 128 + m] : 0.f; break;
          case 2: v = dw2[k * 128 + m]; break;
          case 3: v = cw2[k * 128 + m]; break;
          case 4: v = (m == 0) ? dw3[k] : 0.f; break;
          default: v = (m >= 1 && m <= 3) ? cw3[k * 3 + (m - 1)] : 0.f; break;
        }
        if (h == 0) v0 = v; else v1 = v;
      }
      d[jj] = pack2(v0, v1);
    }
    uint4 o; o.x = d[0]; o.y = d[1]; o.z = d[2]; o.w = d[3];
    wpk[idx] = o;
  }
}

// =====================================================================
// Kernel 2 (round 9): R7's half-granularity staged-weight pipeline
// (proven 382us; R8's quarter granularity regressed: effective LDS
// residency budget is ~128KB/CU so 48KB/block did NOT give 3 blocks).
// ONLY change vs R7: barrier protocol.  R7's __syncthreads = s_waitcnt
// vmcnt(0) + s_barrier placed AFTER the stage it just issued -> drains
// a just-issued stage, exposing full L2 latency at all 11 barriers
// (the m97-structure stall).  New phase shape:
//    [vmcnt(0)+s_barrier]  [issue stage(k+1)]  [compute k]
// The waitcnt now hits a stage issued one full compute-phase earlier
// (already landed).  Safety: stage-issue sits AFTER the barrier, and
// any wave past the barrier has completed its previous-phase ds_reads
// of the target buffer (they fed its MFMAs) -> no write-after-read
// race.  h is wave-private, never needs a barrier.  sched_barrier(0)
// after the inline waitcnt per the compiler-hoist erratum.
// =====================================================================
__device__ __forceinline__ void wait_bar(){
  asm volatile("s_waitcnt vmcnt(0)" ::: "memory");
  __builtin_amdgcn_sched_barrier(0);
  __builtin_amdgcn_s_barrier();
}

__device__ __forceinline__ uint4 blend4(uint4 a, uint4 b, uint4 c, uint4 d,
                                        float w00, float w10, float w01, float w11){
  uint4 ov;
  ov.x = pack2f(w00*bflo(a.x)+w10*bflo(b.x)+w01*bflo(c.x)+w11*bflo(d.x),
                w00*bfhi(a.x)+w10*bfhi(b.x)+w01*bfhi(c.x)+w11*bfhi(d.x));
  ov.y = pack2f(w00*bflo(a.y)+w10*bflo(b.y)+w01*bflo(c.y)+w11*bflo(d.y),
                w00*bfhi(a.y)+w10*bfhi(b.y)+w01*bfhi(c.y)+w11*bfhi(d.y));
  ov.z = pack2f(w00*bflo(a.z)+w10*bflo(b.z)+w01*bflo(c.z)+w11*bflo(d.z),
                w00*bfhi(a.z)+w10*bfhi(b.z)+w01*bfhi(c.z)+w11*bfhi(d.z));
  ov.w = pack2f(w00*bflo(a.w)+w10*bflo(b.w)+w01*bflo(c.w)+w11*bflo(d.w),
                w00*bfhi(a.w)+w10*bfhi(b.w)+w01*bfhi(c.w)+w11*bfhi(d.w));
  return ov;
}

// h layout: row (t*16+lrow) has 64 dwords (128 units); rotation swizzle.
__device__ __forceinline__ bf16x8 read_h(const uint* S, int s, int t, int lrow, int lq){
  int dwb = (s * 16 + lq * 4 + (lrow << 2)) & 63;
  return __builtin_bit_cast(bf16x8, *(const uint4*)&S[(t * 16 + lrow) * 64 + dwb]);
}

__device__ __forceinline__ void put_h(uint* S, f32x4 v, int Mt, int t, int lrow, int lq){
  uint2 w;
  w.x = pack2f(fmaxf(v[0], 0.f), fmaxf(v[1], 0.f));
  w.y = pack2f(fmaxf(v[2], 0.f), fmaxf(v[3], 0.f));
  int dw = (Mt * 8 + lq * 2 + (lrow << 2)) & 63;
  *(uint2*)&S[(t * 16 + lrow) * 64 + dw] = w;
}

// block-cooperative async stage of nchunk*64 uint4 into LDS (4 waves)
__device__ __forceinline__ void stage16(const uint4* __restrict__ g, uint4* l,
                                        int wave, int lane, int nchunk){
  for (int c = wave; c < nchunk; c += 4){
    __builtin_amdgcn_global_load_lds(
      (const __attribute__((address_space(1))) void*)(g + c * 64 + lane),
      (__attribute__((address_space(3))) void*)(l + c * 64 + lane), 16, 0, 0);
  }
}

// one Mt-half (4 Mt-tiles) of an input layer: B-frags from registers
__device__ __forceinline__ void layer1_half(uint* S, const uint4* W,
                                            const float* __restrict__ bias,
                                            const uint4 (&bf)[4][2], int half,
                                            int lrow, int lq, int lane){
  f32x4 acc[4][2];
#pragma unroll
  for (int mt = 0; mt < 4; mt++){
    f32x4 bi = *(const f32x4*)(bias + (half * 4 + mt) * 16 + lq * 4);
    acc[mt][0] = bi; acc[mt][1] = bi;
  }
#pragma unroll
  for (int s = 0; s < 4; s++)
#pragma unroll
    for (int mt = 0; mt < 4; mt++){
      bf16x8 aw = __builtin_bit_cast(bf16x8, W[(mt * 4 + s) * 64 + lane]);
      acc[mt][0] = MFMA16(aw, __builtin_bit_cast(bf16x8, bf[s][0]), acc[mt][0]);
      acc[mt][1] = MFMA16(aw, __builtin_bit_cast(bf16x8, bf[s][1]), acc[mt][1]);
    }
#pragma unroll
  for (int mt = 0; mt < 4; mt++){
    put_h(S, acc[mt][0], half * 4 + mt, 0, lrow, lq);
    put_h(S, acc[mt][1], half * 4 + mt, 1, lrow, lq);
  }
}

__device__ __forceinline__ void load_hb(const uint* S, bf16x8 (&hb)[4][2],
                                        int lrow, int lq){
#pragma unroll
  for (int s = 0; s < 4; s++){
    hb[s][0] = read_h(S, s, 0, lrow, lq);
    hb[s][1] = read_h(S, s, 1, lrow, lq);
  }
}

// one Mt-half of a dense layer: B-frags preloaded (hb), writes in place
__device__ __forceinline__ void dense_half(uint* S, const uint4* W,
                                           const float* __restrict__ bias,
                                           const bf16x8 (&hb)[4][2], int half,
                                           int lrow, int lq, int lane){
  f32x4 acc[4][2];
#pragma unroll
  for (int mt = 0; mt < 4; mt++){
    f32x4 bi = *(const f32x4*)(bias + (half * 4 + mt) * 16 + lq * 4);
    acc[mt][0] = bi; acc[mt][1] = bi;
  }
#pragma unroll
  for (int s = 0; s < 4; s++)
#pragma unroll
    for (int mt = 0; mt < 4; mt++){
      bf16x8 aw = __builtin_bit_cast(bf16x8, W[(mt * 4 + s) * 64 + lane]);
      acc[mt][0] = MFMA16(aw, hb[s][0], acc[mt][0]);
      acc[mt][1] = MFMA16(aw, hb[s][1], acc[mt][1]);
    }
#pragma unroll
  for (int mt = 0; mt < 4; mt++){
    put_h(S, acc[mt][0], half * 4 + mt, 0, lrow, lq);
    put_h(S, acc[mt][1], half * 4 + mt, 1, lrow, lq);
  }
}

__device__ __forceinline__ void out_l(const uint* S, const uint4* W,
                                      f32x4 (&acc3)[2], int lrow, int lq, int lane){
#pragma unroll
  for (int s = 0; s < 4; s++){
    bf16x8 aw = __builtin_bit_cast(bf16x8, W[s * 64 + lane]);
    acc3[0] = MFMA16(aw, read_h(S, s, 0, lrow, lq), acc3[0]);
    acc3[1] = MFMA16(aw, read_h(S, s, 1, lrow, lq), acc3[1]);
  }
}

__global__ __launch_bounds__(256, 2) void fused_k(
    const ushort* __restrict__ tp, const float* __restrict__ coords,
    const float* __restrict__ vdirs, const uint4* __restrict__ wpk,
    const float* __restrict__ db1, const float* __restrict__ db2,
    const float* __restrict__ db3, const float* __restrict__ cb1,
    const float* __restrict__ cb2, const float* __restrict__ cb3,
    float* __restrict__ out)
{
  __shared__ uint  Sh[4][2048];                 // 32 KB: 8 KB wave-private h
  __shared__ uint4 WB[2][1024];                 // 2 x 16 KB weight dbuf
  const int wave = threadIdx.x >> 6;            // 0..3
  uint* S = Sh[wave];
  const int lane = threadIdx.x & 63, lrow = lane & 15, lq = lane >> 4;
  const int blk   = blockIdx.x;                 // 0..8191
  const int pbase = (blk & 3) * 262144 + (blk >> 2) * 128 + wave * 32;

  // prologue: stage w1d.h0 -> B0, under the gather (gather's own
  // compiler waitcnts drain it before first use)
  stage16(wpk + 0, WB[0], wave, lane, 16);

  // ---- fused gather: build B-frags directly in registers ----
  uint4 bf[4][2];
#pragma unroll
  for (int t = 0; t < 2; t++){
    const int p  = pbase + t * 16 + lrow;
    const int bb = p >> 18;                          // N = 2^18
    const float cx = coords[3 * p], cy = coords[3 * p + 1], cz = coords[3 * p + 2];
    float pw00[3], pw10[3], pw01[3], pw11[3];
    uint  o00[3], o10[3], o01[3], o11[3];
#pragma unroll
    for (int pl = 0; pl < 3; pl++){
      const float u = (pl == 2) ? cy : cx;
      const float v = (pl == 0) ? cy : cz;
      float ix = fmaf(u, 128.f, 127.5f);
      float iy = fmaf(v, 128.f, 127.5f);
      float fx0 = floorf(ix), fy0 = floorf(iy);
      float fx = ix - fx0, fy = iy - fy0;
      int x0 = (int)fx0, y0 = (int)fy0;
      float wx0 = (x0 >= 0  && x0 < 256) ? (1.f - fx) : 0.f;
      float wx1 = (x0 >= -1 && x0 < 255) ? fx : 0.f;
      float wy0 = (y0 >= 0  && y0 < 256) ? (1.f - fy) : 0.f;
      float wy1 = (y0 >= -1 && y0 < 255) ? fy : 0.f;
      int xc0 = min(max(x0, 0), 255), xc1 = min(max(x0 + 1, 0), 255);
      int yc0 = min(max(y0, 0), 255), yc1 = min(max(y0 + 1, 0), 255);
      pw00[pl] = wx0 * wy0; pw10[pl] = wx1 * wy0;
      pw01[pl] = wx0 * wy1; pw11[pl] = wx1 * wy1;
      o00[pl] = ((uint)yc0 * 256u + (uint)xc0) * 40u;
      o10[pl] = ((uint)yc0 * 256u + (uint)xc1) * 40u;
      o01[pl] = ((uint)yc1 * 256u + (uint)xc0) * 40u;
      o11[pl] = ((uint)yc1 * 256u + (uint)xc1) * 40u;
    }
#pragma unroll
    for (int s = 0; s < 4; s++){
      const int chunk = s * 4 + lq;        // channel chunk = [chunk*8, chunk*8+7]
      if (chunk == 15){                    // vd + pad (only lq==3, s==3)
        const float v0 = vdirs[3 * p], v1 = vdirs[3 * p + 1], v2 = vdirs[3 * p + 2];
        uint4 tt; tt.x = pack2f(v0, v1); tt.y = pack2f(v2, 0.f); tt.z = 0u; tt.w = 0u;
        bf[s][t] = tt;
      } else {
        const int pl = (chunk < 5) ? 0 : (chunk < 10) ? 1 : 2;
        const int c0 = chunk * 8 - pl * 40;   // local channel offset in plane row
        const ushort* base = tp + (size_t)(bb * 3 + pl) * 2621440 + c0;
        uint4 a = *(const uint4*)(base + o00[pl]);
        uint4 b = *(const uint4*)(base + o10[pl]);
        uint4 c = *(const uint4*)(base + o01[pl]);
        uint4 d = *(const uint4*)(base + o11[pl]);
        bf[s][t] = blend4(a, b, c, d, pw00[pl], pw10[pl], pw01[pl], pw11[pl]);
      }
    }
  }

  f32x4 acc3[2];
  {
    float i0 = (lq == 0) ? db3[0] : 0.f;
    float i1 = (lq == 0) ? cb3[0] : 0.f;
    float i2 = (lq == 0) ? cb3[1] : 0.f;
    float i3 = (lq == 0) ? cb3[2] : 0.f;
    f32x4 iv = {i0, i1, i2, i3};
    acc3[0] = iv; acc3[1] = iv;
  }

  // ---- phase ladder: [wait+barrier][issue next stage][compute] ----
  wait_bar();                                        // B0 = w1d.h0 ready
  stage16(wpk + 1024, WB[1], wave, lane, 16);        // w1d.h1 -> B1
  layer1_half(S, WB[0], db1, bf, 0, lrow, lq, lane);

  wait_bar();                                        // B1 ready; all done w/ B0
  stage16(wpk + 4096, WB[0], wave, lane, 16);        // w2d.h0 -> B0
  layer1_half(S, WB[1], db1, bf, 1, lrow, lq, lane);

  wait_bar();
  stage16(wpk + 5120, WB[1], wave, lane, 16);        // w2d.h1 -> B1
  bf16x8 hb[4][2];
  load_hb(S, hb, lrow, lq);                          // before in-place writes
  dense_half(S, WB[0], db2, hb, 0, lrow, lq, lane);

  wait_bar();
  stage16(wpk + 8192, WB[0], wave, lane, 4);         // w3d -> B0 (4KB)
  dense_half(S, WB[1], db2, hb, 1, lrow, lq, lane);

  wait_bar();
  stage16(wpk + 2048, WB[1], wave, lane, 16);        // w1c.h0 -> B1
  out_l(S, WB[0], acc3, lrow, lq, lane);             // density

  wait_bar();
  stage16(wpk + 3072, WB[0], wave, lane, 16);        // w1c.h1 -> B0
  layer1_half(S, WB[1], cb1, bf, 0, lrow, lq, lane);

  wait_bar();
  stage16(wpk + 6144, WB[1], wave, lane, 16);        // w2c.h0 -> B1
  layer1_half(S, WB[0], cb1, bf, 1, lrow, lq, lane);

  wait_bar();
  stage16(wpk + 7168, WB[0], wave, lane, 16);        // w2c.h1 -> B0
  bf16x8 hb2[4][2];
  load_hb(S, hb2, lrow, lq);
  dense_half(S, WB[1], cb2, hb2, 0, lrow, lq, lane);

  wait_bar();
  stage16(wpk + 8448, WB[1], wave, lane, 4);         // w3c -> B1 (4KB)
  dense_half(S, WB[0], cb2, hb2, 1, lrow, lq, lane);

  wait_bar();
  out_l(S, WB[1], acc3, lrow, lq, lane);             // rgb (no stage)

  if (lq == 0){
#pragma unroll
    for (int t = 0; t < 2; t++){
      int p = pbase + t * 16 + lrow;
      out[p] = acc3[t][0];
      float* rgb = out + 1048576 + (size_t)p * 3;
      rgb[0] = 1.f / (1.f + __expf(-acc3[t][1]));
      rgb[1] = 1.f / (1.f + __expf(-acc3[t][2]));
      rgb[2] = 1.f / (1.f + __expf(-acc3[t][3]));
    }
  }
}

// =====================================================================
extern "C" void kernel_launch(void* const* d_in, const int* in_sizes, int n_in,
                              void* d_out, int out_size, void* d_ws, size_t ws_size,
                              hipStream_t stream)
{
  (void)in_sizes; (void)n_in; (void)out_size; (void)ws_size;
  const float* tri    = (const float*)d_in[0];
  const float* coords = (const float*)d_in[1];
  const float* vdirs  = (const float*)d_in[2];
  const float* dw1 = (const float*)d_in[3];  const float* db1 = (const float*)d_in[4];
  const float* dw2 = (const float*)d_in[5];  const float* db2 = (const float*)d_in[6];
  const float* dw3 = (const float*)d_in[7];  const float* db3 = (const float*)d_in[8];
  const float* cw1 = (const float*)d_in[9];  const float* cb1 = (const float*)d_in[10];
  const float* cw2 = (const float*)d_in[11]; const float* cb2 = (const float*)d_in[12];
  const float* cw3 = (const float*)d_in[13]; const float* cb3 = (const float*)d_in[14];

  char* ws = (char*)d_ws;
  const size_t planes_bytes = 62914560;   // 4*3*256*256*40*2
  ushort* tp  = (ushort*)ws;
  uint4*  wpk = (uint4*)(ws + planes_bytes);

  prep_k<<<3106, 256, 0, stream>>>(tri, tp, dw1, cw1, dw2, cw2, dw3, cw3, wpk);
  fused_k<<<8192, 256, 0, stream>>>(tp, coords, vdirs, wpk,
                                    db1, db2, db3, cb1, cb2, cb3,
                                    (float*)d_out);
}